// Round 1
// baseline (187.259 us; speedup 1.0000x reference)
//
#include <hip/hip_runtime.h>
#include <math.h>

#define NPTS   8192
#define BATCH  2
#define KNN    20
#define COUT   64
#define NCLASS 40

// ---------------------------------------------------------------------------
// Kernel 1: per-batch bitonic sort of 8192 floats in LDS.
// Only sorted VALUES are needed downstream (neighbor order / original indices
// never affect the output: h is max-reduced over k, and pooling over n is
// order-invariant).
// ---------------------------------------------------------------------------
__global__ __launch_bounds__(1024) void sort_kernel(const float* __restrict__ x,
                                                    float* __restrict__ xs) {
    __shared__ float s[NPTS];
    const int b = blockIdx.x;
    const float* xb = x + b * NPTS;
    for (int i = threadIdx.x; i < NPTS; i += 1024) s[i] = xb[i];
    __syncthreads();

    for (int k = 2; k <= NPTS; k <<= 1) {
        for (int j = k >> 1; j > 0; j >>= 1) {
            for (int i = threadIdx.x; i < NPTS; i += 1024) {
                const int ixj = i ^ j;
                if (ixj > i) {
                    const bool up = ((i & k) == 0);
                    const float a = s[i], c = s[ixj];
                    const bool sw = up ? (a > c) : (a < c);
                    if (sw) { s[i] = c; s[ixj] = a; }
                }
            }
            __syncthreads();
        }
    }
    float* out = xs + b * NPTS;
    for (int i = threadIdx.x; i < NPTS; i += 1024) out[i] = s[i];
}

// ---------------------------------------------------------------------------
// Kernel 2: per point p (in sorted order), two-pointer expansion finds the
// contiguous 20-NN window [l, r]; only xs[l] (wmin) and xs[r] (wmax) matter:
//   max_k relu(A*x_m + B*x_n + bias) = relu(A*(A>=0 ? wmax : wmin) + B*x_n + bias)
// Block-reduces max/sum per channel, one atomic per block per channel.
// Grid: BATCH*32 blocks x 256 threads (one thread per point).
// ---------------------------------------------------------------------------
__global__ __launch_bounds__(256) void knn_kernel(const float* __restrict__ xs,
                                                  const float* __restrict__ conv_w,
                                                  const float* __restrict__ bn_g,
                                                  const float* __restrict__ bn_b,
                                                  const float* __restrict__ bn_m,
                                                  const float* __restrict__ bn_v,
                                                  float* __restrict__ maxacc,
                                                  float* __restrict__ sumacc) {
    const int b     = blockIdx.x >> 5;   // 32 blocks per batch
    const int chunk = blockIdx.x & 31;
    const float* xb = xs + b * NPTS;
    const int t = threadIdx.x;
    const int p = chunk * 256 + t;

    const float xn = xb[p];
    int l = p, r = p;
    #pragma unroll
    for (int st = 0; st < KNN - 1; ++st) {
        float pdl = -INFINITY, pdr = -INFINITY;
        if (l > 0) {
            const float xl = xb[l - 1];
            pdl = 2.0f * xn * xl - xn * xn - xl * xl;   // match reference pd formula
        }
        if (r < NPTS - 1) {
            const float xr = xb[r + 1];
            pdr = 2.0f * xn * xr - xn * xn - xr * xr;
        }
        if (pdl >= pdr) --l; else ++r;
    }
    const float wmin = xb[l];
    const float wmax = xb[r];

    __shared__ float sx[256], smin[256], smax[256];
    sx[t] = xn; smin[t] = wmin; smax[t] = wmax;
    __syncthreads();

    // channel c handled by 4 threads (quarters of the 256 points)
    const int c = t & 63, q = t >> 6;
    const float w0 = conv_w[2 * c];
    const float w1 = conv_w[2 * c + 1];
    const float sc = bn_g[c] / sqrtf(bn_v[c] + 1e-5f);
    const float A  = sc * w0;
    const float Bc = sc * (w1 - w0);
    const float bias = bn_b[c] - bn_m[c] * sc;

    float vmax = 0.0f;   // relu outputs are >= 0, so 0-init is exact
    float vsum = 0.0f;
    const int base = q * 64;
    #pragma unroll 8
    for (int i = 0; i < 64; ++i) {
        const int pp = base + i;               // same pp across the wave -> LDS broadcast
        const float w = (A >= 0.0f) ? smax[pp] : smin[pp];
        float h = A * w + Bc * sx[pp] + bias;
        h = fmaxf(h, 0.0f);
        vmax = fmaxf(vmax, h);
        vsum += h;
    }

    __shared__ float pmax[256], psum[256];
    pmax[t] = vmax; psum[t] = vsum;
    __syncthreads();
    if (t < 64) {
        const float m = fmaxf(fmaxf(pmax[t], pmax[t + 64]),
                              fmaxf(pmax[t + 128], pmax[t + 192]));
        const float su = psum[t] + psum[t + 64] + psum[t + 128] + psum[t + 192];
        // all values >= 0.0f: uint-reinterpret atomicMax is order-preserving
        atomicMax((unsigned int*)&maxacc[b * COUT + t], __float_as_uint(m));
        atomicAdd(&sumacc[b * COUT + t], su);
    }
}

// ---------------------------------------------------------------------------
// Kernel 3: head matmul. out[b, j] = sum_c x1[b,c]*lw[j,c] + x2[b,c]*lw[j,64+c]
// ---------------------------------------------------------------------------
__global__ __launch_bounds__(128) void head_kernel(const float* __restrict__ maxacc,
                                                   const float* __restrict__ sumacc,
                                                   const float* __restrict__ lin_w,
                                                   float* __restrict__ out) {
    const int t = threadIdx.x;
    if (t >= BATCH * NCLASS) return;
    const int b = t / NCLASS, j = t % NCLASS;
    const float* lw = lin_w + j * (2 * COUT);
    float acc = 0.0f;
    #pragma unroll
    for (int c = 0; c < COUT; ++c) acc += maxacc[b * COUT + c] * lw[c];
    #pragma unroll
    for (int c = 0; c < COUT; ++c)
        acc += (sumacc[b * COUT + c] * (1.0f / (float)NPTS)) * lw[COUT + c];
    out[b * NCLASS + j] = acc;
}

extern "C" void kernel_launch(void* const* d_in, const int* in_sizes, int n_in,
                              void* d_out, int out_size, void* d_ws, size_t ws_size,
                              hipStream_t stream) {
    const float* x      = (const float*)d_in[0];   // (2, 8192)
    const float* conv_w = (const float*)d_in[1];   // (64, 2)
    const float* bn_g   = (const float*)d_in[2];   // (64,)
    const float* bn_b   = (const float*)d_in[3];
    const float* bn_m   = (const float*)d_in[4];
    const float* bn_v   = (const float*)d_in[5];
    const float* lin_w  = (const float*)d_in[6];   // (40, 128)
    float* out = (float*)d_out;                    // (2, 40) fp32

    // ws layout: sorted values [2*8192], then max acc [2*64], sum acc [2*64]
    float* xs     = (float*)d_ws;
    float* maxacc = xs + BATCH * NPTS;
    float* sumacc = maxacc + BATCH * COUT;

    hipMemsetAsync(maxacc, 0, 2 * BATCH * COUT * sizeof(float), stream);
    sort_kernel<<<BATCH, 1024, 0, stream>>>(x, xs);
    knn_kernel<<<BATCH * 32, 256, 0, stream>>>(xs, conv_w, bn_g, bn_b, bn_m, bn_v,
                                               maxacc, sumacc);
    head_kernel<<<1, 128, 0, stream>>>(maxacc, sumacc, lin_w, out);
}

// Round 2
// 103.468 us; speedup vs baseline: 1.8098x; 1.8098x over previous
//
#include <hip/hip_runtime.h>
#include <math.h>

#define NPTS   8192
#define BATCH  2
#define KNN    20
#define COUT   64
#define NCLASS 40

// compare-exchange: a=lower index, b=upper index
__device__ __forceinline__ void ce(float& a, float& b, bool up) {
    const float lo = fminf(a, b), hi = fmaxf(a, b);
    a = up ? lo : hi;
    b = up ? hi : lo;
}

// ---------------------------------------------------------------------------
// Kernel 1: per-batch bitonic sort of 8192 floats, register-resident.
// Thread t owns elements i = 8t..8t+7 in v[0..7].
//   j in {1,2,4}   -> in-register        (36 phases, no barrier)
//   j in {8..256}  -> __shfl_xor in-wave (45 phases, no barrier)
//   j in {512..4096}-> LDS vector swap   (10 phases, 2 barriers each)
// ---------------------------------------------------------------------------
__global__ __launch_bounds__(1024) void sort_kernel(const float* __restrict__ x,
                                                    float* __restrict__ xs) {
    __shared__ float sx[1024 * 9];   // stride-9 padding: conflict-free vector swap
    const int b = blockIdx.x;
    const int t = threadIdx.x;

    float v[8];
    const float4* xv = (const float4*)(x + b * NPTS + t * 8);
    const float4 a0 = xv[0], a1 = xv[1];
    v[0]=a0.x; v[1]=a0.y; v[2]=a0.z; v[3]=a0.w;
    v[4]=a1.x; v[5]=a1.y; v[6]=a1.z; v[7]=a1.w;

    // stage k=2 (j=1), directions ((i&k)==0), i = 8t+q
    ce(v[0],v[1],true);  ce(v[2],v[3],false); ce(v[4],v[5],true);  ce(v[6],v[7],false);
    // stage k=4 (j=2,1)
    ce(v[0],v[2],true);  ce(v[1],v[3],true);  ce(v[4],v[6],false); ce(v[5],v[7],false);
    ce(v[0],v[1],true);  ce(v[2],v[3],true);  ce(v[4],v[5],false); ce(v[6],v[7],false);
    // stage k=8 (j=4,2,1), direction uniform per thread: ((8t)&8)==0 -> t even
    {
        const bool u8 = ((t & 1) == 0);
        ce(v[0],v[4],u8); ce(v[1],v[5],u8); ce(v[2],v[6],u8); ce(v[3],v[7],u8);
        ce(v[0],v[2],u8); ce(v[1],v[3],u8); ce(v[4],v[6],u8); ce(v[5],v[7],u8);
        ce(v[0],v[1],u8); ce(v[2],v[3],u8); ce(v[4],v[5],u8); ce(v[6],v[7],u8);
    }

    for (int k = 16; k <= NPTS; k <<= 1) {
        const bool up = (t & (k >> 3)) == 0;   // ((8t)&k)==0, uniform in thread

        // cross-wave phases via LDS 8-vector exchange
        for (int j = k >> 1; j >= 512; j >>= 1) {
            const int lm = j >> 3;             // partner thread offset (>=64)
            __syncthreads();                   // protect previous phase's reads
            #pragma unroll
            for (int q = 0; q < 8; ++q) sx[t * 9 + q] = v[q];
            __syncthreads();
            const int pt = t ^ lm;
            const bool tmin = up ^ ((t & lm) != 0);
            #pragma unroll
            for (int q = 0; q < 8; ++q) {
                const float o = sx[pt * 9 + q];
                v[q] = tmin ? fminf(v[q], o) : fmaxf(v[q], o);
            }
        }
        // in-wave phases via shuffle
        {
            const int j0 = (k >> 1) < 256 ? (k >> 1) : 256;
            for (int j = j0; j >= 8; j >>= 1) {
                const int lm = j >> 3;         // 1..32, stays in wave
                const bool tmin = up ^ ((t & lm) != 0);
                #pragma unroll
                for (int q = 0; q < 8; ++q) {
                    const float o = __shfl_xor(v[q], lm, 64);
                    v[q] = tmin ? fminf(v[q], o) : fmaxf(v[q], o);
                }
            }
        }
        // in-register phases j=4,2,1 (uniform direction for k>=16)
        ce(v[0],v[4],up); ce(v[1],v[5],up); ce(v[2],v[6],up); ce(v[3],v[7],up);
        ce(v[0],v[2],up); ce(v[1],v[3],up); ce(v[4],v[6],up); ce(v[5],v[7],up);
        ce(v[0],v[1],up); ce(v[2],v[3],up); ce(v[4],v[5],up); ce(v[6],v[7],up);
    }

    float4* ov = (float4*)(xs + b * NPTS + t * 8);
    ov[0] = make_float4(v[0], v[1], v[2], v[3]);
    ov[1] = make_float4(v[4], v[5], v[6], v[7]);
}

// ---------------------------------------------------------------------------
// Kernel 2: two-pointer 20-NN window on the sorted array (values only), then
// folded conv+BN+relu with max/sum pooling. Same logic as the passing round-1
// kernel; sorted region staged in LDS so the serial chain hits LDS.
// ---------------------------------------------------------------------------
__global__ __launch_bounds__(256) void knn_kernel(const float* __restrict__ xs,
                                                  const float* __restrict__ conv_w,
                                                  const float* __restrict__ bn_g,
                                                  const float* __restrict__ bn_b,
                                                  const float* __restrict__ bn_m,
                                                  const float* __restrict__ bn_v,
                                                  float* __restrict__ maxacc,
                                                  float* __restrict__ sumacc) {
    const int b     = blockIdx.x >> 5;
    const int chunk = blockIdx.x & 31;
    const int t     = threadIdx.x;
    const int base  = chunk * 256;
    const int off   = base - 32;               // ls[i] <-> global index off+i
    const float* xb = xs + b * NPTS;

    __shared__ float ls[320];                  // [base-32, base+288)
    {
        const int gi = off + t;
        ls[t] = (gi >= 0 && gi < NPTS) ? xb[gi] : 0.0f;
        if (t < 64) {
            const int gi2 = base + 224 + t;
            ls[256 + t] = (gi2 < NPTS) ? xb[gi2] : 0.0f;
        }
    }
    __syncthreads();

    const int p = base + t;
    const float xn = ls[t + 32];
    int l = p, r = p;
    #pragma unroll
    for (int st = 0; st < KNN - 1; ++st) {
        float pdl = -INFINITY, pdr = -INFINITY;
        if (l > 0) {
            const float xl = ls[l - 1 - off];
            pdl = 2.0f * xn * xl - xn * xn - xl * xl;   // reference pd formula
        }
        if (r < NPTS - 1) {
            const float xr = ls[r + 1 - off];
            pdr = 2.0f * xn * xr - xn * xn - xr * xr;
        }
        if (pdl >= pdr) --l; else ++r;
    }

    __shared__ float sxp[256], smin[256], smax[256];
    sxp[t] = xn; smin[t] = ls[l - off]; smax[t] = ls[r - off];
    __syncthreads();

    const int c = t & 63, q = t >> 6;
    const float w0 = conv_w[2 * c];
    const float w1 = conv_w[2 * c + 1];
    const float sc = bn_g[c] / sqrtf(bn_v[c] + 1e-5f);
    const float A  = sc * w0;
    const float Bc = sc * (w1 - w0);
    const float bias = bn_b[c] - bn_m[c] * sc;
    const float* warr = (A >= 0.0f) ? smax : smin;  // relu+max monotonicity

    float vmax = 0.0f, vsum = 0.0f;
    const int bse = q * 64;
    #pragma unroll 8
    for (int i = 0; i < 64; ++i) {
        const int pp = bse + i;
        float h = A * warr[pp] + Bc * sxp[pp] + bias;
        h = fmaxf(h, 0.0f);
        vmax = fmaxf(vmax, h);
        vsum += h;
    }

    __shared__ float pmax[256], psum[256];
    pmax[t] = vmax; psum[t] = vsum;
    __syncthreads();
    if (t < 64) {
        const float m  = fmaxf(fmaxf(pmax[t], pmax[t + 64]),
                               fmaxf(pmax[t + 128], pmax[t + 192]));
        const float su = psum[t] + psum[t + 64] + psum[t + 128] + psum[t + 192];
        atomicMax((unsigned int*)&maxacc[b * COUT + t], __float_as_uint(m));
        atomicAdd(&sumacc[b * COUT + t], su);
    }
}

// ---------------------------------------------------------------------------
// Kernel 3: head matmul. out[b,j] = sum_c x1[b,c]*lw[j,c] + mean[b,c]*lw[j,64+c]
// ---------------------------------------------------------------------------
__global__ __launch_bounds__(128) void head_kernel(const float* __restrict__ maxacc,
                                                   const float* __restrict__ sumacc,
                                                   const float* __restrict__ lin_w,
                                                   float* __restrict__ out) {
    const int t = threadIdx.x;
    if (t >= BATCH * NCLASS) return;
    const int b = t / NCLASS, j = t % NCLASS;
    const float* lw = lin_w + j * (2 * COUT);
    float acc = 0.0f;
    #pragma unroll
    for (int c = 0; c < COUT; ++c) acc += maxacc[b * COUT + c] * lw[c];
    #pragma unroll
    for (int c = 0; c < COUT; ++c)
        acc += (sumacc[b * COUT + c] * (1.0f / (float)NPTS)) * lw[COUT + c];
    out[b * NCLASS + j] = acc;
}

extern "C" void kernel_launch(void* const* d_in, const int* in_sizes, int n_in,
                              void* d_out, int out_size, void* d_ws, size_t ws_size,
                              hipStream_t stream) {
    const float* x      = (const float*)d_in[0];
    const float* conv_w = (const float*)d_in[1];
    const float* bn_g   = (const float*)d_in[2];
    const float* bn_b   = (const float*)d_in[3];
    const float* bn_m   = (const float*)d_in[4];
    const float* bn_v   = (const float*)d_in[5];
    const float* lin_w  = (const float*)d_in[6];
    float* out = (float*)d_out;

    float* xs     = (float*)d_ws;
    float* maxacc = xs + BATCH * NPTS;
    float* sumacc = maxacc + BATCH * COUT;

    hipMemsetAsync(maxacc, 0, 2 * BATCH * COUT * sizeof(float), stream);
    sort_kernel<<<BATCH, 1024, 0, stream>>>(x, xs);
    knn_kernel<<<BATCH * 32, 256, 0, stream>>>(xs, conv_w, bn_g, bn_b, bn_m, bn_v,
                                               maxacc, sumacc);
    head_kernel<<<1, 128, 0, stream>>>(maxacc, sumacc, lin_w, out);
}